// Round 5
// baseline (2516.935 us; speedup 1.0000x reference)
//
#include <hip/hip_runtime.h>
#include <hip/hip_fp16.h>
#include <math.h>

typedef _Float16 half_t;
typedef half_t half4_t __attribute__((ext_vector_type(4)));
typedef half_t half8_t __attribute__((ext_vector_type(8)));
typedef float f32x4 __attribute__((ext_vector_type(4)));

#define LN_EPS 1e-5f

// ---------------------------------------------------------------------------
// Pack W*g (LN gain folded) into f16 MFMA B-fragment order:
//   packed[((cbg*T + t)*64 + l)*8 + j] = (f16)(W[16*cbg+(l&15)][32t+8*(l>>4)+j] * g[k])
// ---------------------------------------------------------------------------
__global__ void pack_weights(const float* __restrict__ W0, const float* __restrict__ g0,
                             const float* __restrict__ W1, const float* __restrict__ g1,
                             const float* __restrict__ W2, const float* __restrict__ g2,
                             half_t* __restrict__ ws) {
    int sid = blockIdx.x * 256 + threadIdx.x;
    const float* W; const float* g; int K, T, off;
    if (sid < 49152)      { W = W0; g = g0; K = 768; T = 24; off = 0; }
    else if (sid < 65536) { W = W1; g = g1; K = 512; T = 16; off = 49152; sid -= 49152; }
    else if (sid < 69632) { W = W2; g = g2; K = 256; T = 8;  off = 65536; sid -= 65536; }
    else return;
    const int l   = sid & 63;
    const int t   = (sid >> 6) % T;
    const int cbg = (sid >> 6) / T;
    const int n   = (l & 15) + 16 * cbg;
    const int k0  = 32 * t + 8 * (l >> 4);
    const float* src = W + (size_t)n * K + k0;
    const float* gs  = g + k0;
    half8_t v;
    #pragma unroll
    for (int jq = 0; jq < 8; jq++) v[jq] = (half_t)(src[jq] * gs[jq]);
    *(half8_t*)(ws + (size_t)(off + sid) * 8) = v;
}

// ---------------------------------------------------------------------------
// Fold LN bias into per-output scalars: s[n]=sum_k W[n,k]*g[k],
// c'[n]=sum_k W[n,k]*b[k]+c[n]. f layout:
// s0[512] c0[512] s1[256] c1[256] s2[128] c2[128] w3g[128] s3 c3'
// ---------------------------------------------------------------------------
__global__ void fold_bias(const float* __restrict__ W0, const float* __restrict__ g0,
                          const float* __restrict__ b0, const float* __restrict__ c0,
                          const float* __restrict__ W1, const float* __restrict__ g1,
                          const float* __restrict__ b1, const float* __restrict__ c1,
                          const float* __restrict__ W2, const float* __restrict__ g2,
                          const float* __restrict__ b2, const float* __restrict__ c2,
                          const float* __restrict__ W3, const float* __restrict__ g3,
                          const float* __restrict__ b3, const float* __restrict__ c3,
                          float* __restrict__ f) {
    const int gw   = (blockIdx.x * 256 + threadIdx.x) >> 6;
    const int lane = threadIdx.x & 63;
    if (gw == 896) {
        float s = 0.f, cb_ = 0.f;
        for (int k = lane; k < 128; k += 64) {
            const float wg = W3[k] * g3[k];
            f[1792 + k] = wg;
            s += wg; cb_ += W3[k] * b3[k];
        }
        #pragma unroll
        for (int m = 1; m < 64; m <<= 1) { s += __shfl_xor(s, m); cb_ += __shfl_xor(cb_, m); }
        if (lane == 0) { f[1920] = s; f[1921] = cb_ + c3[0]; }
        return;
    }
    const float *W, *g, *b, *cc; int K, n; float *sf, *cf;
    if (gw < 512)      { W = W0; g = g0; b = b0; cc = c0; K = 768; n = gw;       sf = f;        cf = f + 512; }
    else if (gw < 768) { W = W1; g = g1; b = b1; cc = c1; K = 512; n = gw - 512; sf = f + 1024; cf = f + 1280; }
    else if (gw < 896) { W = W2; g = g2; b = b2; cc = c2; K = 256; n = gw - 768; sf = f + 1536; cf = f + 1664; }
    else return;
    const float* Wr = W + (size_t)n * K;
    float s = 0.f, cb_ = 0.f;
    for (int k = lane; k < K; k += 64) { const float wg = Wr[k] * g[k]; s += wg; cb_ += Wr[k] * b[k]; }
    #pragma unroll
    for (int m = 1; m < 64; m <<= 1) { s += __shfl_xor(s, m); cb_ += __shfl_xor(cb_, m); }
    if (lane == 0) { sf[n] = s; cf[n] = cb_ + cc[n]; }
}

// ---------------------------------------------------------------------------
// Kernel 1: layer0 only. Stream x (HBM), GEMM vs W0g (L2), LN0-fold + ELU,
// write y to global IN MFMA A-FRAGMENT ORDER (via 2-pass LDS transpose) so
// kernel2 can load it linearly. Homogeneous phases -> grid-level overlap.
// ---------------------------------------------------------------------------
__global__ __launch_bounds__(512, 4)
void k1_gemm0(const float* __restrict__ x_in, const half_t* __restrict__ W0p,
              const float* __restrict__ f, half_t* __restrict__ y_g)
{
    __shared__ half_t sbuf[16384];                 // 32 KiB: 2x8192 staging, reused for out-transpose
    __shared__ float row_m[64], row_rs[64];

    const int tid  = threadIdx.x;
    const int lane = tid & 63;
    const int wv   = tid >> 6;       // 0..7
    const int grp  = lane >> 4;
    const int cl   = lane & 15;
    const int row  = tid >> 3;       // staging row 0..63
    const int jj   = tid & 7;
    const int rbw  = row >> 4;
    const long r0  = (long)blockIdx.x * 64;
    const float* xrow = x_in + (r0 + row) * 768;
    const float* s0f = f; const float* c0f = f + 512;

    float s = 0.f, ss = 0.f;
    f32x4 vb[4];

    auto stage_load = [&](int c) {
        const float* xp = xrow + 128 * c + 4 * jj;
        #pragma unroll
        for (int i = 0; i < 4; i++)
            vb[i] = __builtin_nontemporal_load((const f32x4*)(xp + 32 * i));
    };
    auto stage_write = [&](int c) {
        half_t* fb = sbuf + 8192 * (c & 1);
        const int hg = jj >> 1, jo = 4 * (jj & 1);
        #pragma unroll
        for (int i = 0; i < 4; i++) {
            const f32x4 v = vb[i];
            s  += v[0] + v[1] + v[2] + v[3];
            ss += v[0]*v[0] + v[1]*v[1] + v[2]*v[2] + v[3]*v[3];
            half4_t hv;
            hv[0] = (half_t)v[0]; hv[1] = (half_t)v[1];
            hv[2] = (half_t)v[2]; hv[3] = (half_t)v[3];
            *(half4_t*)(&fb[((i * 4 + rbw) * 64 + ((row & 15) + 16 * hg)) * 8 + jo]) = hv;
        }
    };

    f32x4 acc0[4][4];
    #pragma unroll
    for (int rb = 0; rb < 4; rb++)
        #pragma unroll
        for (int cb = 0; cb < 4; cb++) acc0[rb][cb] = 0.f;

    auto gemm0 = [&](int c) {
        const half_t* fb = sbuf + 8192 * (c & 1);
        const half_t* wp = W0p + (size_t)(4 * wv * 24 + 4 * c) * 512 + lane * 8;
        half8_t bA[4], bB[4];
        #pragma unroll
        for (int cb = 0; cb < 4; cb++) bA[cb] = *(const half8_t*)(wp + cb * 12288);
        #pragma unroll
        for (int tt = 0; tt < 4; tt++) {
            half8_t* cur = (tt & 1) ? bB : bA;
            half8_t* nxt = (tt & 1) ? bA : bB;
            if (tt < 3) {
                #pragma unroll
                for (int cb = 0; cb < 4; cb++)
                    nxt[cb] = *(const half8_t*)(wp + (tt + 1) * 512 + cb * 12288);
            }
            half8_t af[4];
            #pragma unroll
            for (int rb = 0; rb < 4; rb++)
                af[rb] = *(const half8_t*)(&fb[((tt * 4 + rb) * 64 + lane) * 8]);
            #pragma unroll
            for (int cb = 0; cb < 4; cb++)
                #pragma unroll
                for (int rb = 0; rb < 4; rb++)
                    acc0[rb][cb] = __builtin_amdgcn_mfma_f32_16x16x32_f16(af[rb], cur[cb], acc0[rb][cb], 0, 0, 0);
        }
    };

    // pipeline over 6 K-chunks of 128
    stage_load(0); stage_write(0);
    __syncthreads();
    #pragma unroll 1
    for (int c = 0; c < 6; c++) {
        if (c < 5) stage_load(c + 1);
        gemm0(c);
        if (c < 5) stage_write(c + 1);
        if (c == 4) {
            s  += __shfl_xor(s, 1);  s  += __shfl_xor(s, 2);  s  += __shfl_xor(s, 4);
            ss += __shfl_xor(ss, 1); ss += __shfl_xor(ss, 2); ss += __shfl_xor(ss, 4);
            if (jj == 0) {
                const float mm = s * (1.f / 768.f);
                row_m[row]  = mm;
                row_rs[row] = 1.f / sqrtf(ss * (1.f / 768.f) - mm * mm + LN_EPS);
            }
        }
        __syncthreads();
    }

    // epilogue: LN0 fold + ELU (all in regs)
    {
        float sv[4], cv[4];
        #pragma unroll
        for (int cb = 0; cb < 4; cb++) {
            const int c = cl + 16 * (4 * wv + cb);
            sv[cb] = s0f[c]; cv[cb] = c0f[c];
        }
        #pragma unroll
        for (int rb = 0; rb < 4; rb++)
            #pragma unroll
            for (int v = 0; v < 4; v++) {
                const int r = 16 * rb + 4 * grp + v;
                const float rm = row_m[r], rr = row_rs[r];
                #pragma unroll
                for (int cb = 0; cb < 4; cb++) {
                    float y = rr * (acc0[rb][cb][v] - rm * sv[cb]) + cv[cb];
                    acc0[rb][cb][v] = y > 0.f ? y : (__expf(y) - 1.f);
                }
            }
    }

    // 2-pass transpose-out: pass p covers t = 2*wv + p (cb pair {2p,2p+1})
    const long yb = (long)blockIdx.x * 32768;
    #pragma unroll 1
    for (int p = 0; p < 2; p++) {
        __syncthreads();       // sbuf free (gemm / previous pass's LDS reads done)
        #pragma unroll
        for (int cbl = 0; cbl < 2; cbl++) {
            const int cb = 2 * p + cbl;
            const int c  = cl + 16 * (4 * wv + cb);
            const int j  = c & 7, sc = 16 * ((c >> 3) & 3);
            #pragma unroll
            for (int rb = 0; rb < 4; rb++)
                #pragma unroll
                for (int v = 0; v < 4; v++)
                    sbuf[((wv * 4 + rb) * 64 + (4 * grp + v + sc)) * 8 + j] = (half_t)acc0[rb][cb][v];
        }
        __syncthreads();
        #pragma unroll
        for (int i = 0; i < 4; i++) {
            const int u  = tid + 512 * i;                     // local 16B unit
            const float4 val = *(const float4*)(sbuf + u * 8);
            const int gu = ((2 * (u >> 8) + p) << 8) + (u & 255);   // global 16B unit
            *(float4*)(y_g + yb + (long)gu * 8) = val;
        }
    }
}

// ---------------------------------------------------------------------------
// Kernel 2: layers 1-3. Load y (already in A-fragment order) linearly into
// LDS, scan for LN1 stats, then R4-proven gemm1/epi1/gemm2/epi2/out chain.
// ---------------------------------------------------------------------------
__global__ __launch_bounds__(512, 4)
void k2_tail(const half_t* __restrict__ y_g, const half_t* __restrict__ W1p,
             const half_t* __restrict__ W2p, const float* __restrict__ f,
             float* __restrict__ out)
{
    __shared__ half_t frag[32768];                 // 64 KiB y; x2 aliases [0,16384) after gemm1
    __shared__ float psum[8][64], psq[8][64], pdot[8][64];
    __shared__ float row_m[64], row_rs[64];

    const int tid  = threadIdx.x;
    const int lane = tid & 63;
    const int wv   = tid >> 6;
    const int grp  = lane >> 4;
    const int cl   = lane & 15;
    const int row  = tid >> 3;
    const int jj   = tid & 7;
    const long r0  = (long)blockIdx.x * 64;
    const long yb  = (long)blockIdx.x * 32768;

    const float* s1f = f + 1024; const float* c1f = f + 1280;
    const float* s2f = f + 1536; const float* c2f = f + 1664;
    const float* w3f = f + 1792;

    // ---- load y tile into LDS (linear, coalesced) ----
    {
        f32x4 t0[8];
        #pragma unroll
        for (int i = 0; i < 8; i++)
            t0[i] = __builtin_nontemporal_load((const f32x4*)(y_g + yb + (size_t)(tid + 512 * i) * 8));
        #pragma unroll
        for (int i = 0; i < 8; i++)
            *(f32x4*)(frag + (size_t)(tid + 512 * i) * 8) = t0[i];
    }
    __syncthreads();

    // ---- LN1 stats scan: 8 threads/row, 8 half8-chunks each ----
    {
        const int r15 = row & 15, rb = row >> 4;
        float s_ = 0.f, q_ = 0.f;
        #pragma unroll
        for (int i = 0; i < 8; i++) {
            const int ch = jj + 8 * i;            // 64 chunks/row: t = ch>>2, colgrp = ch&3
            const int t = ch >> 2, cg = ch & 3;
            const half8_t h = *(const half8_t*)(frag + (size_t)((t * 4 + rb) * 64 + r15 + 16 * cg) * 8);
            #pragma unroll
            for (int e = 0; e < 8; e++) { const float fv = (float)h[e]; s_ += fv; q_ += fv * fv; }
        }
        s_ += __shfl_xor(s_, 1); s_ += __shfl_xor(s_, 2); s_ += __shfl_xor(s_, 4);
        q_ += __shfl_xor(q_, 1); q_ += __shfl_xor(q_, 2); q_ += __shfl_xor(q_, 4);
        if (jj == 0) {
            const float mm = s_ * (1.f / 512.f);
            row_m[row]  = mm;
            row_rs[row] = 1.f / sqrtf(q_ * (1.f / 512.f) - mm * mm + LN_EPS);
        }
    }
    __syncthreads();

    // ---- GEMM1: K=512 (16 t-steps), wave owns 32 cols, B prefetched ----
    f32x4 acc1[4][2];
    #pragma unroll
    for (int rb = 0; rb < 4; rb++) { acc1[rb][0] = 0.f; acc1[rb][1] = 0.f; }
    {
        const half_t* wp = W1p + (size_t)(2 * wv * 16) * 512 + lane * 8;
        half8_t bA[2], bB[2];
        bA[0] = *(const half8_t*)(wp);
        bA[1] = *(const half8_t*)(wp + 8192);
        #pragma unroll
        for (int t = 0; t < 16; t++) {
            half8_t* cur = (t & 1) ? bB : bA;
            half8_t* nxt = (t & 1) ? bA : bB;
            if (t < 15) {
                nxt[0] = *(const half8_t*)(wp + (t + 1) * 512);
                nxt[1] = *(const half8_t*)(wp + (t + 1) * 512 + 8192);
            }
            half8_t af[4];
            #pragma unroll
            for (int rb = 0; rb < 4; rb++)
                af[rb] = *(const half8_t*)(&frag[((t * 4 + rb) * 64 + lane) * 8]);
            #pragma unroll
            for (int cb = 0; cb < 2; cb++)
                #pragma unroll
                for (int rb = 0; rb < 4; rb++)
                    acc1[rb][cb] = __builtin_amdgcn_mfma_f32_16x16x32_f16(af[rb], cur[cb], acc1[rb][cb], 0, 0, 0);
        }
    }

    // ---- epilogue1: LN1 fold + ELU + LN2 partials ----
    {
        float sv[2], cv[2];
        #pragma unroll
        for (int cb = 0; cb < 2; cb++) {
            const int c = cl + 16 * (2 * wv + cb);
            sv[cb] = s1f[c]; cv[cb] = c1f[c];
        }
        #pragma unroll
        for (int rb = 0; rb < 4; rb++)
            #pragma unroll
            for (int v = 0; v < 4; v++) {
                const int r = 16 * rb + 4 * grp + v;
                const float rm = row_m[r], rr = row_rs[r];
                float a_ = 0.f, q_ = 0.f;
                #pragma unroll
                for (int cb = 0; cb < 2; cb++) {
                    float y = rr * (acc1[rb][cb][v] - rm * sv[cb]) + cv[cb];
                    y = y > 0.f ? y : (__expf(y) - 1.f);
                    acc1[rb][cb][v] = y;
                    a_ += y; q_ += y * y;
                }
                a_ += __shfl_xor(a_, 1); a_ += __shfl_xor(a_, 2); a_ += __shfl_xor(a_, 4); a_ += __shfl_xor(a_, 8);
                q_ += __shfl_xor(q_, 1); q_ += __shfl_xor(q_, 2); q_ += __shfl_xor(q_, 4); q_ += __shfl_xor(q_, 8);
                if (cl == 0) { psum[wv][r] = a_; psq[wv][r] = q_; }
            }
    }
    __syncthreads();   // gemm1 readers done -> frag[0,16K) reusable; psum published

    // ---- x2 fragment writes + LN2 finalize ----
    #pragma unroll
    for (int cb = 0; cb < 2; cb++) {
        const int c = cl + 16 * (2 * wv + cb);
        const int t = c >> 5, j = c & 7, sc = 16 * ((c >> 3) & 3);
        #pragma unroll
        for (int rb = 0; rb < 4; rb++)
            #pragma unroll
            for (int v = 0; v < 4; v++)
                frag[((t * 4 + rb) * 64 + (4 * grp + v + sc)) * 8 + j] = (half_t)acc1[rb][cb][v];
    }
    if (tid < 64) {
        float a_ = 0.f, q_ = 0.f;
        #pragma unroll
        for (int w = 0; w < 8; w++) { a_ += psum[w][tid]; q_ += psq[w][tid]; }
        const float mm = a_ * (1.f / 256.f);
        row_m[tid]  = mm;
        row_rs[tid] = 1.f / sqrtf(q_ * (1.f / 256.f) - mm * mm + LN_EPS);
    }
    __syncthreads();

    // ---- GEMM2: K=256 (8 t-steps), wave owns 16 cols ----
    f32x4 acc2[4];
    #pragma unroll
    for (int rb = 0; rb < 4; rb++) acc2[rb] = 0.f;
    {
        const half_t* wp = W2p + (size_t)(wv * 8) * 512 + lane * 8;
        half8_t bA = *(const half8_t*)(wp);
        #pragma unroll
        for (int t = 0; t < 8; t++) {
            const half8_t cur = bA;
            if (t < 7) bA = *(const half8_t*)(wp + (t + 1) * 512);
            half8_t af[4];
            #pragma unroll
            for (int rb = 0; rb < 4; rb++)
                af[rb] = *(const half8_t*)(&frag[((t * 4 + rb) * 64 + lane) * 8]);
            #pragma unroll
            for (int rb = 0; rb < 4; rb++)
                acc2[rb] = __builtin_amdgcn_mfma_f32_16x16x32_f16(af[rb], cur, acc2[rb], 0, 0, 0);
        }
    }

    // ---- epilogue2: LN2 fold + ELU + LN3 partials + folded W3 dot ----
    {
        const int c2i = cl + 16 * wv;
        const float sv = s2f[c2i], cv = c2f[c2i], w3v = w3f[c2i];
        #pragma unroll
        for (int rb = 0; rb < 4; rb++)
            #pragma unroll
            for (int v = 0; v < 4; v++) {
                const int r = 16 * rb + 4 * grp + v;
                const float rm = row_m[r], rr = row_rs[r];
                float y = rr * (acc2[rb][v] - rm * sv) + cv;
                y = y > 0.f ? y : (__expf(y) - 1.f);
                float a_ = y, q_ = y * y, d_ = y * w3v;
                a_ += __shfl_xor(a_, 1); a_ += __shfl_xor(a_, 2); a_ += __shfl_xor(a_, 4); a_ += __shfl_xor(a_, 8);
                q_ += __shfl_xor(q_, 1); q_ += __shfl_xor(q_, 2); q_ += __shfl_xor(q_, 4); q_ += __shfl_xor(q_, 8);
                d_ += __shfl_xor(d_, 1); d_ += __shfl_xor(d_, 2); d_ += __shfl_xor(d_, 4); d_ += __shfl_xor(d_, 8);
                if (cl == 0) { psum[wv][r] = a_; psq[wv][r] = q_; pdot[wv][r] = d_; }
            }
    }
    __syncthreads();
    if (tid < 64) {
        float a_ = 0.f, q_ = 0.f, d_ = 0.f;
        #pragma unroll
        for (int w = 0; w < 8; w++) { a_ += psum[w][tid]; q_ += psq[w][tid]; d_ += pdot[w][tid]; }
        const float mm = a_ * (1.f / 128.f);
        const float rs = 1.f / sqrtf(q_ * (1.f / 128.f) - mm * mm + LN_EPS);
        out[r0 + tid] = rs * (d_ - mm * f[1920]) + f[1921];
    }
}

// ---------------------------------------------------------------------------
// Fallback monolith (R4, proven): used if d_ws cannot hold the y buffer.
// ---------------------------------------------------------------------------
__global__ __launch_bounds__(512, 4)
void fused_mlp(const float* __restrict__ x_in,
               const half_t* __restrict__ W0p, const half_t* __restrict__ W1p,
               const half_t* __restrict__ W2p, const float* __restrict__ f,
               float* __restrict__ out)
{
    __shared__ half_t frag[32768];
    __shared__ float psum[8][64], psq[8][64], pdot[8][64];
    __shared__ float row_m[64], row_rs[64];

    const int tid  = threadIdx.x;
    const int lane = tid & 63;
    const int wv   = tid >> 6;
    const int grp  = lane >> 4;
    const int cl   = lane & 15;
    const int row  = tid >> 3;
    const int jj   = tid & 7;
    const int rbw  = row >> 4;
    const long r0  = (long)blockIdx.x * 64;
    const float* xrow = x_in + (r0 + row) * 768;

    const float* s0f = f;        const float* c0f = f + 512;
    const float* s1f = f + 1024; const float* c1f = f + 1280;
    const float* s2f = f + 1536; const float* c2f = f + 1664;
    const float* w3f = f + 1792;

    float s = 0.f, ss = 0.f;
    f32x4 vb[4];

    auto stage_load = [&](int c) {
        const float* xp = xrow + 128 * c + 4 * jj;
        #pragma unroll
        for (int i = 0; i < 4; i++)
            vb[i] = __builtin_nontemporal_load((const f32x4*)(xp + 32 * i));
    };
    auto stage_write = [&](int c) {
        half_t* fb = frag + 8192 * (c & 1);
        const int hg = jj >> 1, jo = 4 * (jj & 1);
        #pragma unroll
        for (int i = 0; i < 4; i++) {
            const f32x4 v = vb[i];
            s  += v[0] + v[1] + v[2] + v[3];
            ss += v[0]*v[0] + v[1]*v[1] + v[2]*v[2] + v[3]*v[3];
            half4_t hv;
            hv[0] = (half_t)v[0]; hv[1] = (half_t)v[1];
            hv[2] = (half_t)v[2]; hv[3] = (half_t)v[3];
            *(half4_t*)(&fb[((i * 4 + rbw) * 64 + ((row & 15) + 16 * hg)) * 8 + jo]) = hv;
        }
    };

    f32x4 acc0[4][4];
    #pragma unroll
    for (int rb = 0; rb < 4; rb++)
        #pragma unroll
        for (int cb = 0; cb < 4; cb++) acc0[rb][cb] = 0.f;

    auto gemm0 = [&](int c) {
        const half_t* fb = frag + 8192 * (c & 1);
        const half_t* wp = W0p + (size_t)(4 * wv * 24 + 4 * c) * 512 + lane * 8;
        half8_t bA[4], bB[4];
        #pragma unroll
        for (int cb = 0; cb < 4; cb++) bA[cb] = *(const half8_t*)(wp + cb * 12288);
        #pragma unroll
        for (int tt = 0; tt < 4; tt++) {
            half8_t* cur = (tt & 1) ? bB : bA;
            half8_t* nxt = (tt & 1) ? bA : bB;
            if (tt < 3) {
                #pragma unroll
                for (int cb = 0; cb < 4; cb++)
                    nxt[cb] = *(const half8_t*)(wp + (tt + 1) * 512 + cb * 12288);
            }
            half8_t af[4];
            #pragma unroll
            for (int rb = 0; rb < 4; rb++)
                af[rb] = *(const half8_t*)(&fb[((tt * 4 + rb) * 64 + lane) * 8]);
            #pragma unroll
            for (int cb = 0; cb < 4; cb++)
                #pragma unroll
                for (int rb = 0; rb < 4; rb++)
                    acc0[rb][cb] = __builtin_amdgcn_mfma_f32_16x16x32_f16(af[rb], cur[cb], acc0[rb][cb], 0, 0, 0);
        }
    };

    stage_load(0); stage_write(0);
    __syncthreads();
    #pragma unroll 1
    for (int c = 0; c < 6; c++) {
        if (c < 5) stage_load(c + 1);
        gemm0(c);
        if (c < 5) stage_write(c + 1);
        if (c == 4) {
            s  += __shfl_xor(s, 1);  s  += __shfl_xor(s, 2);  s  += __shfl_xor(s, 4);
            ss += __shfl_xor(ss, 1); ss += __shfl_xor(ss, 2); ss += __shfl_xor(ss, 4);
            if (jj == 0) {
                const float mm = s * (1.f / 768.f);
                row_m[row]  = mm;
                row_rs[row] = 1.f / sqrtf(ss * (1.f / 768.f) - mm * mm + LN_EPS);
            }
        }
        __syncthreads();
    }

    {
        float sv[4], cv[4];
        #pragma unroll
        for (int cb = 0; cb < 4; cb++) {
            const int c = cl + 16 * (4 * wv + cb);
            sv[cb] = s0f[c]; cv[cb] = c0f[c];
        }
        #pragma unroll
        for (int rb = 0; rb < 4; rb++)
            #pragma unroll
            for (int v = 0; v < 4; v++) {
                const int r = 16 * rb + 4 * grp + v;
                const float rm = row_m[r], rr = row_rs[r];
                float a_ = 0.f, q_ = 0.f;
                #pragma unroll
                for (int cb = 0; cb < 4; cb++) {
                    float y = rr * (acc0[rb][cb][v] - rm * sv[cb]) + cv[cb];
                    y = y > 0.f ? y : (__expf(y) - 1.f);
                    acc0[rb][cb][v] = y;
                    a_ += y; q_ += y * y;
                }
                a_ += __shfl_xor(a_, 1); a_ += __shfl_xor(a_, 2); a_ += __shfl_xor(a_, 4); a_ += __shfl_xor(a_, 8);
                q_ += __shfl_xor(q_, 1); q_ += __shfl_xor(q_, 2); q_ += __shfl_xor(q_, 4); q_ += __shfl_xor(q_, 8);
                if (cl == 0) { psum[wv][r] = a_; psq[wv][r] = q_; }
            }
        #pragma unroll
        for (int cb = 0; cb < 4; cb++) {
            const int c = cl + 16 * (4 * wv + cb);
            const int t = c >> 5, j = c & 7, sc = 16 * ((c >> 3) & 3);
            #pragma unroll
            for (int rb = 0; rb < 4; rb++)
                #pragma unroll
                for (int v = 0; v < 4; v++)
                    frag[((t * 4 + rb) * 64 + (4 * grp + v + sc)) * 8 + j] = (half_t)acc0[rb][cb][v];
        }
    }
    __syncthreads();
    if (tid < 64) {
        float a_ = 0.f, q_ = 0.f;
        #pragma unroll
        for (int w = 0; w < 8; w++) { a_ += psum[w][tid]; q_ += psq[w][tid]; }
        const float mm = a_ * (1.f / 512.f);
        row_m[tid]  = mm;
        row_rs[tid] = 1.f / sqrtf(q_ * (1.f / 512.f) - mm * mm + LN_EPS);
    }
    __syncthreads();

    f32x4 acc1[4][2];
    #pragma unroll
    for (int rb = 0; rb < 4; rb++) { acc1[rb][0] = 0.f; acc1[rb][1] = 0.f; }
    {
        const half_t* wp = W1p + (size_t)(2 * wv * 16) * 512 + lane * 8;
        half8_t bA[2], bB[2];
        bA[0] = *(const half8_t*)(wp);
        bA[1] = *(const half8_t*)(wp + 8192);
        #pragma unroll
        for (int t = 0; t < 16; t++) {
            half8_t* cur = (t & 1) ? bB : bA;
            half8_t* nxt = (t & 1) ? bA : bB;
            if (t < 15) {
                nxt[0] = *(const half8_t*)(wp + (t + 1) * 512);
                nxt[1] = *(const half8_t*)(wp + (t + 1) * 512 + 8192);
            }
            half8_t af[4];
            #pragma unroll
            for (int rb = 0; rb < 4; rb++)
                af[rb] = *(const half8_t*)(&frag[((t * 4 + rb) * 64 + lane) * 8]);
            #pragma unroll
            for (int cb = 0; cb < 2; cb++)
                #pragma unroll
                for (int rb = 0; rb < 4; rb++)
                    acc1[rb][cb] = __builtin_amdgcn_mfma_f32_16x16x32_f16(af[rb], cur[cb], acc1[rb][cb], 0, 0, 0);
        }
    }

    {
        float sv[2], cv[2];
        #pragma unroll
        for (int cb = 0; cb < 2; cb++) {
            const int c = cl + 16 * (2 * wv + cb);
            sv[cb] = s1f[c]; cv[cb] = c1f[c];
        }
        #pragma unroll
        for (int rb = 0; rb < 4; rb++)
            #pragma unroll
            for (int v = 0; v < 4; v++) {
                const int r = 16 * rb + 4 * grp + v;
                const float rm = row_m[r], rr = row_rs[r];
                float a_ = 0.f, q_ = 0.f;
                #pragma unroll
                for (int cb = 0; cb < 2; cb++) {
                    float y = rr * (acc1[rb][cb][v] - rm * sv[cb]) + cv[cb];
                    y = y > 0.f ? y : (__expf(y) - 1.f);
                    acc1[rb][cb][v] = y;
                    a_ += y; q_ += y * y;
                }
                a_ += __shfl_xor(a_, 1); a_ += __shfl_xor(a_, 2); a_ += __shfl_xor(a_, 4); a_ += __shfl_xor(a_, 8);
                q_ += __shfl_xor(q_, 1); q_ += __shfl_xor(q_, 2); q_ += __shfl_xor(q_, 4); q_ += __shfl_xor(q_, 8);
                if (cl == 0) { psum[wv][r] = a_; psq[wv][r] = q_; }
            }
    }
    __syncthreads();
    #pragma unroll
    for (int cb = 0; cb < 2; cb++) {
        const int c = cl + 16 * (2 * wv + cb);
        const int t = c >> 5, j = c & 7, sc = 16 * ((c >> 3) & 3);
        #pragma unroll
        for (int rb = 0; rb < 4; rb++)
            #pragma unroll
            for (int v = 0; v < 4; v++)
                frag[((t * 4 + rb) * 64 + (4 * grp + v + sc)) * 8 + j] = (half_t)acc1[rb][cb][v];
    }
    if (tid < 64) {
        float a_ = 0.f, q_ = 0.f;
        #pragma unroll
        for (int w = 0; w < 8; w++) { a_ += psum[w][tid]; q_ += psq[w][tid]; }
        const float mm = a_ * (1.f / 256.f);
        row_m[tid]  = mm;
        row_rs[tid] = 1.f / sqrtf(q_ * (1.f / 256.f) - mm * mm + LN_EPS);
    }
    __syncthreads();

    f32x4 acc2[4];
    #pragma unroll
    for (int rb = 0; rb < 4; rb++) acc2[rb] = 0.f;
    {
        const half_t* wp = W2p + (size_t)(wv * 8) * 512 + lane * 8;
        half8_t bA = *(const half8_t*)(wp);
        #pragma unroll
        for (int t = 0; t < 8; t++) {
            const half8_t cur = bA;
            if (t < 7) bA = *(const half8_t*)(wp + (t + 1) * 512);
            half8_t af[4];
            #pragma unroll
            for (int rb = 0; rb < 4; rb++)
                af[rb] = *(const half8_t*)(&frag[((t * 4 + rb) * 64 + lane) * 8]);
            #pragma unroll
            for (int rb = 0; rb < 4; rb++)
                acc2[rb] = __builtin_amdgcn_mfma_f32_16x16x32_f16(af[rb], cur, acc2[rb], 0, 0, 0);
        }
    }

    {
        const int c2i = cl + 16 * wv;
        const float sv = s2f[c2i], cv = c2f[c2i], w3v = w3f[c2i];
        #pragma unroll
        for (int rb = 0; rb < 4; rb++)
            #pragma unroll
            for (int v = 0; v < 4; v++) {
                const int r = 16 * rb + 4 * grp + v;
                const float rm = row_m[r], rr = row_rs[r];
                float y = rr * (acc2[rb][v] - rm * sv) + cv;
                y = y > 0.f ? y : (__expf(y) - 1.f);
                float a_ = y, q_ = y * y, d_ = y * w3v;
                a_ += __shfl_xor(a_, 1); a_ += __shfl_xor(a_, 2); a_ += __shfl_xor(a_, 4); a_ += __shfl_xor(a_, 8);
                q_ += __shfl_xor(q_, 1); q_ += __shfl_xor(q_, 2); q_ += __shfl_xor(q_, 4); q_ += __shfl_xor(q_, 8);
                d_ += __shfl_xor(d_, 1); d_ += __shfl_xor(d_, 2); d_ += __shfl_xor(d_, 4); d_ += __shfl_xor(d_, 8);
                if (cl == 0) { psum[wv][r] = a_; psq[wv][r] = q_; pdot[wv][r] = d_; }
            }
    }
    __syncthreads();
    if (tid < 64) {
        float a_ = 0.f, q_ = 0.f, d_ = 0.f;
        #pragma unroll
        for (int w = 0; w < 8; w++) { a_ += psum[w][tid]; q_ += psq[w][tid]; d_ += pdot[w][tid]; }
        const float mm = a_ * (1.f / 128.f);
        const float rs = 1.f / sqrtf(q_ * (1.f / 128.f) - mm * mm + LN_EPS);
        out[r0 + tid] = rs * (d_ - mm * f[1920]) + f[1921];
    }
}

extern "C" void kernel_launch(void* const* d_in, const int* in_sizes, int n_in,
                              void* d_out, int out_size, void* d_ws, size_t ws_size,
                              hipStream_t stream) {
    const float* x  = (const float*)d_in[0];
    const float* g0 = (const float*)d_in[1];
    const float* b0 = (const float*)d_in[2];
    const float* W0 = (const float*)d_in[3];
    const float* c0 = (const float*)d_in[4];
    const float* g1 = (const float*)d_in[5];
    const float* b1 = (const float*)d_in[6];
    const float* W1 = (const float*)d_in[7];
    const float* c1 = (const float*)d_in[8];
    const float* g2 = (const float*)d_in[9];
    const float* b2 = (const float*)d_in[10];
    const float* W2 = (const float*)d_in[11];
    const float* c2 = (const float*)d_in[12];
    const float* g3 = (const float*)d_in[13];
    const float* b3 = (const float*)d_in[14];
    const float* W3 = (const float*)d_in[15];
    const float* c3 = (const float*)d_in[16];

    half_t* ws  = (half_t*)d_ws;           // packed weights: 557056 halves
    float*  f   = (float*)(ws + 557056);   // folded scalars: 1922 floats
    half_t* y_g = ws + 561152;             // y buffer: 262144*512 halves (268 MB)

    pack_weights<<<272, 256, 0, stream>>>(W0, g0, W1, g1, W2, g2, ws);
    fold_bias<<<225, 256, 0, stream>>>(W0, g0, b0, c0, W1, g1, b1, c1,
                                       W2, g2, b2, c2, W3, g3, b3, c3, f);

    const int nrows = in_sizes[0] / 768;   // 262144
    const size_t NEED = (size_t)561152 * 2 + (size_t)nrows * 512 * 2 + 4096;
    if (ws_size >= NEED) {
        k1_gemm0<<<nrows / 64, 512, 0, stream>>>(x, ws, f, y_g);
        k2_tail<<<nrows / 64, 512, 0, stream>>>(y_g, ws + 393216, ws + 524288, f, (float*)d_out);
    } else {
        fused_mlp<<<nrows / 64, 512, 0, stream>>>(
            x, ws, ws + 393216, ws + 524288, f, (float*)d_out);
    }
}

// Round 6
// 547.953 us; speedup vs baseline: 4.5933x; 4.5933x over previous
//
#include <hip/hip_runtime.h>
#include <hip/hip_fp16.h>
#include <math.h>

typedef _Float16 half_t;
typedef half_t half4_t __attribute__((ext_vector_type(4)));
typedef half_t half8_t __attribute__((ext_vector_type(8)));
typedef float f32x4 __attribute__((ext_vector_type(4)));

#define LN_EPS 1e-5f

// ---------------------------------------------------------------------------
// Pack W*g (LN gain folded) into f16 MFMA B-fragment order:
//   packed[((cbg*T + t)*64 + l)*8 + j] = (f16)(W[16*cbg+(l&15)][32t+8*(l>>4)+j] * g[k])
// ---------------------------------------------------------------------------
__global__ void pack_weights(const float* __restrict__ W0, const float* __restrict__ g0,
                             const float* __restrict__ W1, const float* __restrict__ g1,
                             const float* __restrict__ W2, const float* __restrict__ g2,
                             half_t* __restrict__ ws) {
    int sid = blockIdx.x * 256 + threadIdx.x;
    const float* W; const float* g; int K, T, off;
    if (sid < 49152)      { W = W0; g = g0; K = 768; T = 24; off = 0; }
    else if (sid < 65536) { W = W1; g = g1; K = 512; T = 16; off = 49152; sid -= 49152; }
    else if (sid < 69632) { W = W2; g = g2; K = 256; T = 8;  off = 65536; sid -= 65536; }
    else return;
    const int l   = sid & 63;
    const int t   = (sid >> 6) % T;
    const int cbg = (sid >> 6) / T;
    const int n   = (l & 15) + 16 * cbg;
    const int k0  = 32 * t + 8 * (l >> 4);
    const float* src = W + (size_t)n * K + k0;
    const float* gs  = g + k0;
    half8_t v;
    #pragma unroll
    for (int jq = 0; jq < 8; jq++) v[jq] = (half_t)(src[jq] * gs[jq]);
    *(half8_t*)(ws + (size_t)(off + sid) * 8) = v;
}

// ---------------------------------------------------------------------------
// Fold LN bias into per-output scalars: s[n]=sum_k W[n,k]*g[k],
// c'[n]=sum_k W[n,k]*b[k]+c[n]. f layout:
// s0[512] c0[512] s1[256] c1[256] s2[128] c2[128] w3g[128] s3 c3'
// ---------------------------------------------------------------------------
__global__ void fold_bias(const float* __restrict__ W0, const float* __restrict__ g0,
                          const float* __restrict__ b0, const float* __restrict__ c0,
                          const float* __restrict__ W1, const float* __restrict__ g1,
                          const float* __restrict__ b1, const float* __restrict__ c1,
                          const float* __restrict__ W2, const float* __restrict__ g2,
                          const float* __restrict__ b2, const float* __restrict__ c2,
                          const float* __restrict__ W3, const float* __restrict__ g3,
                          const float* __restrict__ b3, const float* __restrict__ c3,
                          float* __restrict__ f) {
    const int gw   = (blockIdx.x * 256 + threadIdx.x) >> 6;
    const int lane = threadIdx.x & 63;
    if (gw == 896) {
        float s = 0.f, cb_ = 0.f;
        for (int k = lane; k < 128; k += 64) {
            const float wg = W3[k] * g3[k];
            f[1792 + k] = wg;
            s += wg; cb_ += W3[k] * b3[k];
        }
        #pragma unroll
        for (int m = 1; m < 64; m <<= 1) { s += __shfl_xor(s, m); cb_ += __shfl_xor(cb_, m); }
        if (lane == 0) { f[1920] = s; f[1921] = cb_ + c3[0]; }
        return;
    }
    const float *W, *g, *b, *cc; int K, n; float *sf, *cf;
    if (gw < 512)      { W = W0; g = g0; b = b0; cc = c0; K = 768; n = gw;       sf = f;        cf = f + 512; }
    else if (gw < 768) { W = W1; g = g1; b = b1; cc = c1; K = 512; n = gw - 512; sf = f + 1024; cf = f + 1280; }
    else if (gw < 896) { W = W2; g = g2; b = b2; cc = c2; K = 256; n = gw - 768; sf = f + 1536; cf = f + 1664; }
    else return;
    const float* Wr = W + (size_t)n * K;
    float s = 0.f, cb_ = 0.f;
    for (int k = lane; k < K; k += 64) { const float wg = Wr[k] * g[k]; s += wg; cb_ += Wr[k] * b[k]; }
    #pragma unroll
    for (int m = 1; m < 64; m <<= 1) { s += __shfl_xor(s, m); cb_ += __shfl_xor(cb_, m); }
    if (lane == 0) { sf[n] = s; cf[n] = cb_ + cc[n]; }
}

// ---------------------------------------------------------------------------
// Fused MLP v6: 64 rows/block, 512 threads (8 waves), 2 blocks/CU.
// LN folded into weights (GEMMs on raw f16 activations).
// ALL LN reductions are LDS scans of the f16 fragment tiles (8 threads/row,
// ds_read_b128), replacing ~450 __shfl_xor DS-ops per wave with ~30.
// ---------------------------------------------------------------------------
__global__ __launch_bounds__(512, 4)
void fused_mlp(const float* __restrict__ x_in,
               const half_t* __restrict__ W0p, const half_t* __restrict__ W1p,
               const half_t* __restrict__ W2p, const float* __restrict__ f,
               float* __restrict__ out)
{
    __shared__ half_t frag[32768];       // 64 KiB: staging aliases [0,16384); x1 full; x2 [0,16384); y3 [0,8704)
    __shared__ float row_m[64], row_rs[64];
    __shared__ float w3s[128];

    const int tid  = threadIdx.x;
    const int lane = tid & 63;
    const int wv   = tid >> 6;       // wave 0..7
    const int grp  = lane >> 4;
    const int cl   = lane & 15;
    const int row  = tid >> 3;       // 0..63 (staging/scan row)
    const int jj   = tid & 7;        // 8 threads per row
    const int rbw  = row >> 4;
    const long r0  = (long)blockIdx.x * 64;
    const float* xrow = x_in + (r0 + row) * 768;

    const float* s0f = f;        const float* c0f = f + 512;
    const float* s1f = f + 1024; const float* c1f = f + 1280;
    const float* s2f = f + 1536; const float* c2f = f + 1664;

    if (tid < 128) w3s[tid] = f[1792 + tid];    // folded W3*g3

    float s = 0.f, ss = 0.f;
    f32x4 vb[4];

    auto stage_load = [&](int c) {
        const float* xp = xrow + 128 * c + 4 * jj;
        #pragma unroll
        for (int i = 0; i < 4; i++)
            vb[i] = __builtin_nontemporal_load((const f32x4*)(xp + 32 * i));
    };
    auto stage_write = [&](int c) {
        half_t* fb = frag + 8192 * (c & 1);
        const int hg = jj >> 1, jo = 4 * (jj & 1);
        #pragma unroll
        for (int i = 0; i < 4; i++) {
            const f32x4 v = vb[i];
            s  += v[0] + v[1] + v[2] + v[3];
            ss += v[0]*v[0] + v[1]*v[1] + v[2]*v[2] + v[3]*v[3];
            half4_t hv;
            hv[0] = (half_t)v[0]; hv[1] = (half_t)v[1];
            hv[2] = (half_t)v[2]; hv[3] = (half_t)v[3];
            *(half4_t*)(&fb[((i * 4 + rbw) * 64 + ((row & 15) + 16 * hg)) * 8 + jo]) = hv;
        }
    };

    f32x4 acc0[4][4];
    #pragma unroll
    for (int rb = 0; rb < 4; rb++)
        #pragma unroll
        for (int cb = 0; cb < 4; cb++) acc0[rb][cb] = 0.f;

    auto gemm0 = [&](int c) {
        const half_t* fb = frag + 8192 * (c & 1);
        const half_t* wp = W0p + (size_t)(4 * wv * 24 + 4 * c) * 512 + lane * 8;
        half8_t bA[4], bB[4];
        #pragma unroll
        for (int cb = 0; cb < 4; cb++) bA[cb] = *(const half8_t*)(wp + cb * 12288);
        #pragma unroll
        for (int tt = 0; tt < 4; tt++) {
            half8_t* cur = (tt & 1) ? bB : bA;
            half8_t* nxt = (tt & 1) ? bA : bB;
            if (tt < 3) {
                #pragma unroll
                for (int cb = 0; cb < 4; cb++)
                    nxt[cb] = *(const half8_t*)(wp + (tt + 1) * 512 + cb * 12288);
            }
            half8_t af[4];
            #pragma unroll
            for (int rb = 0; rb < 4; rb++)
                af[rb] = *(const half8_t*)(&fb[((tt * 4 + rb) * 64 + lane) * 8]);
            #pragma unroll
            for (int cb = 0; cb < 4; cb++)
                #pragma unroll
                for (int rb = 0; rb < 4; rb++)
                    acc0[rb][cb] = __builtin_amdgcn_mfma_f32_16x16x32_f16(af[rb], cur[cb], acc0[rb][cb], 0, 0, 0);
        }
    };

    // ---- layer-0 pipeline: 6 chunks of K=128 ----
    stage_load(0); stage_write(0);
    __syncthreads();
    #pragma unroll 1
    for (int c = 0; c < 6; c++) {
        if (c < 5) stage_load(c + 1);
        gemm0(c);
        if (c < 5) stage_write(c + 1);
        if (c == 4) {
            s  += __shfl_xor(s, 1);  s  += __shfl_xor(s, 2);  s  += __shfl_xor(s, 4);
            ss += __shfl_xor(ss, 1); ss += __shfl_xor(ss, 2); ss += __shfl_xor(ss, 4);
            if (jj == 0) {
                const float mm = s * (1.f / 768.f);
                row_m[row]  = mm;
                row_rs[row] = 1.f / sqrtf(ss * (1.f / 768.f) - mm * mm + LN_EPS);
            }
        }
        __syncthreads();
    }

    // ---- epilogue0: LN0 fold + ELU + write x1 fragments (no reductions) ----
    {
        float sv[4], cv[4];
        #pragma unroll
        for (int cb = 0; cb < 4; cb++) {
            const int c = cl + 16 * (4 * wv + cb);
            sv[cb] = s0f[c]; cv[cb] = c0f[c];
        }
        #pragma unroll
        for (int rb = 0; rb < 4; rb++)
            #pragma unroll
            for (int v = 0; v < 4; v++) {
                const int r = 16 * rb + 4 * grp + v;
                const float rm = row_m[r], rr = row_rs[r];
                #pragma unroll
                for (int cb = 0; cb < 4; cb++) {
                    float y = rr * (acc0[rb][cb][v] - rm * sv[cb]) + cv[cb];
                    acc0[rb][cb][v] = y > 0.f ? y : (__expf(y) - 1.f);
                }
            }
        #pragma unroll
        for (int cb = 0; cb < 4; cb++) {
            const int c = cl + 16 * (4 * wv + cb);
            const int t = c >> 5, j = c & 7, sc = 16 * ((c >> 3) & 3);
            #pragma unroll
            for (int rb = 0; rb < 4; rb++)
                #pragma unroll
                for (int v = 0; v < 4; v++)
                    frag[((t * 4 + rb) * 64 + (4 * grp + v + sc)) * 8 + j] = (half_t)acc0[rb][cb][v];
        }
    }
    __syncthreads();

    // ---- LN1 stats: LDS scan of x1 (512 cols, 8 threads/row, 8 chunks) ----
    {
        const int r15 = row & 15, rb = row >> 4;
        float s_ = 0.f, q_ = 0.f;
        #pragma unroll
        for (int i = 0; i < 8; i++) {
            const int ch = jj + 8 * i;
            const int t = ch >> 2, cg = ch & 3;
            const half8_t h = *(const half8_t*)(frag + (size_t)((t * 4 + rb) * 64 + r15 + 16 * cg) * 8);
            #pragma unroll
            for (int e = 0; e < 8; e++) { const float fv = (float)h[e]; s_ += fv; q_ += fv * fv; }
        }
        s_ += __shfl_xor(s_, 1); s_ += __shfl_xor(s_, 2); s_ += __shfl_xor(s_, 4);
        q_ += __shfl_xor(q_, 1); q_ += __shfl_xor(q_, 2); q_ += __shfl_xor(q_, 4);
        if (jj == 0) {
            const float mm = s_ * (1.f / 512.f);
            row_m[row]  = mm;
            row_rs[row] = 1.f / sqrtf(q_ * (1.f / 512.f) - mm * mm + LN_EPS);
        }
    }

    // ---- GEMM1: K=512 (16 t-steps), wave owns 32 cols, B prefetched ----
    f32x4 acc1[4][2];
    #pragma unroll
    for (int rb = 0; rb < 4; rb++) { acc1[rb][0] = 0.f; acc1[rb][1] = 0.f; }
    {
        const half_t* wp = W1p + (size_t)(2 * wv * 16) * 512 + lane * 8;
        half8_t bA[2], bB[2];
        bA[0] = *(const half8_t*)(wp);
        bA[1] = *(const half8_t*)(wp + 8192);
        #pragma unroll
        for (int t = 0; t < 16; t++) {
            half8_t* cur = (t & 1) ? bB : bA;
            half8_t* nxt = (t & 1) ? bA : bB;
            if (t < 15) {
                nxt[0] = *(const half8_t*)(wp + (t + 1) * 512);
                nxt[1] = *(const half8_t*)(wp + (t + 1) * 512 + 8192);
            }
            half8_t af[4];
            #pragma unroll
            for (int rb = 0; rb < 4; rb++)
                af[rb] = *(const half8_t*)(&frag[((t * 4 + rb) * 64 + lane) * 8]);
            #pragma unroll
            for (int cb = 0; cb < 2; cb++)
                #pragma unroll
                for (int rb = 0; rb < 4; rb++)
                    acc1[rb][cb] = __builtin_amdgcn_mfma_f32_16x16x32_f16(af[rb], cur[cb], acc1[rb][cb], 0, 0, 0);
        }
    }
    __syncthreads();   // gemm1 + scan reads done; row stats visible

    // ---- epilogue1: LN1 fold + ELU + write x2 fragments ----
    {
        float sv[2], cv[2];
        #pragma unroll
        for (int cb = 0; cb < 2; cb++) {
            const int c = cl + 16 * (2 * wv + cb);
            sv[cb] = s1f[c]; cv[cb] = c1f[c];
        }
        #pragma unroll
        for (int rb = 0; rb < 4; rb++)
            #pragma unroll
            for (int v = 0; v < 4; v++) {
                const int r = 16 * rb + 4 * grp + v;
                const float rm = row_m[r], rr = row_rs[r];
                #pragma unroll
                for (int cb = 0; cb < 2; cb++) {
                    float y = rr * (acc1[rb][cb][v] - rm * sv[cb]) + cv[cb];
                    acc1[rb][cb][v] = y > 0.f ? y : (__expf(y) - 1.f);
                }
            }
        #pragma unroll
        for (int cb = 0; cb < 2; cb++) {
            const int c = cl + 16 * (2 * wv + cb);
            const int t = c >> 5, j = c & 7, sc = 16 * ((c >> 3) & 3);
            #pragma unroll
            for (int rb = 0; rb < 4; rb++)
                #pragma unroll
                for (int v = 0; v < 4; v++)
                    frag[((t * 4 + rb) * 64 + (4 * grp + v + sc)) * 8 + j] = (half_t)acc1[rb][cb][v];
        }
    }
    __syncthreads();

    // ---- LN2 stats: LDS scan of x2 (256 cols, 8 threads/row, 4 chunks) ----
    {
        const int r15 = row & 15, rb = row >> 4;
        float s_ = 0.f, q_ = 0.f;
        #pragma unroll
        for (int i = 0; i < 4; i++) {
            const int ch = jj + 8 * i;
            const int t = ch >> 2, cg = ch & 3;
            const half8_t h = *(const half8_t*)(frag + (size_t)((t * 4 + rb) * 64 + r15 + 16 * cg) * 8);
            #pragma unroll
            for (int e = 0; e < 8; e++) { const float fv = (float)h[e]; s_ += fv; q_ += fv * fv; }
        }
        s_ += __shfl_xor(s_, 1); s_ += __shfl_xor(s_, 2); s_ += __shfl_xor(s_, 4);
        q_ += __shfl_xor(q_, 1); q_ += __shfl_xor(q_, 2); q_ += __shfl_xor(q_, 4);
        if (jj == 0) {
            const float mm = s_ * (1.f / 256.f);
            row_m[row]  = mm;
            row_rs[row] = 1.f / sqrtf(q_ * (1.f / 256.f) - mm * mm + LN_EPS);
        }
    }

    // ---- GEMM2: K=256 (8 t-steps), wave owns 16 cols ----
    f32x4 acc2[4];
    #pragma unroll
    for (int rb = 0; rb < 4; rb++) acc2[rb] = 0.f;
    {
        const half_t* wp = W2p + (size_t)(wv * 8) * 512 + lane * 8;
        half8_t bA = *(const half8_t*)(wp);
        #pragma unroll
        for (int t = 0; t < 8; t++) {
            const half8_t cur = bA;
            if (t < 7) bA = *(const half8_t*)(wp + (t + 1) * 512);
            half8_t af[4];
            #pragma unroll
            for (int rb = 0; rb < 4; rb++)
                af[rb] = *(const half8_t*)(&frag[((t * 4 + rb) * 64 + lane) * 8]);
            #pragma unroll
            for (int rb = 0; rb < 4; rb++)
                acc2[rb] = __builtin_amdgcn_mfma_f32_16x16x32_f16(af[rb], cur, acc2[rb], 0, 0, 0);
        }
    }
    __syncthreads();   // gemm2 + scan2 reads done; row stats visible

    // ---- epilogue2: LN2 fold + ELU -> y3 tile [64][136] in LDS ----
    {
        const int c2i = cl + 16 * wv;
        const float sv = s2f[c2i], cv = c2f[c2i];
        #pragma unroll
        for (int rb = 0; rb < 4; rb++)
            #pragma unroll
            for (int v = 0; v < 4; v++) {
                const int r = 16 * rb + 4 * grp + v;
                const float rm = row_m[r], rr = row_rs[r];
                float y = rr * (acc2[rb][v] - rm * sv) + cv;
                y = y > 0.f ? y : (__expf(y) - 1.f);
                frag[r * 136 + c2i] = (half_t)y;
            }
    }
    __syncthreads();

    // ---- LN3 scan + folded W3 dot + output (8 threads/row, 16 cols each) ----
    {
        float s_ = 0.f, q_ = 0.f, d_ = 0.f;
        #pragma unroll
        for (int u = 0; u < 2; u++) {
            const int cb = jj * 16 + 8 * u;
            const half8_t h = *(const half8_t*)(frag + row * 136 + cb);
            #pragma unroll
            for (int e = 0; e < 8; e++) {
                const float fv = (float)h[e];
                s_ += fv; q_ += fv * fv; d_ += fv * w3s[cb + e];
            }
        }
        s_ += __shfl_xor(s_, 1); s_ += __shfl_xor(s_, 2); s_ += __shfl_xor(s_, 4);
        q_ += __shfl_xor(q_, 1); q_ += __shfl_xor(q_, 2); q_ += __shfl_xor(q_, 4);
        d_ += __shfl_xor(d_, 1); d_ += __shfl_xor(d_, 2); d_ += __shfl_xor(d_, 4);
        if (jj == 0) {
            const float mm = s_ * (1.f / 128.f);
            const float rs = 1.f / sqrtf(q_ * (1.f / 128.f) - mm * mm + LN_EPS);
            out[r0 + row] = rs * (d_ - mm * f[1920]) + f[1921];
        }
    }
}

extern "C" void kernel_launch(void* const* d_in, const int* in_sizes, int n_in,
                              void* d_out, int out_size, void* d_ws, size_t ws_size,
                              hipStream_t stream) {
    const float* x  = (const float*)d_in[0];
    const float* g0 = (const float*)d_in[1];
    const float* b0 = (const float*)d_in[2];
    const float* W0 = (const float*)d_in[3];
    const float* c0 = (const float*)d_in[4];
    const float* g1 = (const float*)d_in[5];
    const float* b1 = (const float*)d_in[6];
    const float* W1 = (const float*)d_in[7];
    const float* c1 = (const float*)d_in[8];
    const float* g2 = (const float*)d_in[9];
    const float* b2 = (const float*)d_in[10];
    const float* W2 = (const float*)d_in[11];
    const float* c2 = (const float*)d_in[12];
    const float* g3 = (const float*)d_in[13];
    const float* b3 = (const float*)d_in[14];
    const float* W3 = (const float*)d_in[15];
    const float* c3 = (const float*)d_in[16];

    half_t* ws = (half_t*)d_ws;            // packed weights: 557056 halves
    float*  f  = (float*)(ws + 557056);    // folded scalars: 1922 floats

    pack_weights<<<272, 256, 0, stream>>>(W0, g0, W1, g1, W2, g2, ws);
    fold_bias<<<225, 256, 0, stream>>>(W0, g0, b0, c0, W1, g1, b1, c1,
                                       W2, g2, b2, c2, W3, g3, b3, c3, f);

    const int nrows = in_sizes[0] / 768;   // 262144
    fused_mlp<<<nrows / 64, 512, 0, stream>>>(
        x, ws, ws + 393216, ws + 524288, f, (float*)d_out);
}